// Round 2
// baseline (2722.928 us; speedup 1.0000x reference)
//
#include <hip/hip_runtime.h>

#define NN 50000      // nodes
#define NR 10         // relations (one direction)
#define R2 21         // 2*NR+1
#define NE 500000     // triples
#define NB 16384      // batch
#define HID 64

// ---------------- count: histogram over col for fwd+bwd edges -----------------
__global__ void count_kernel(const int* __restrict__ triples, int* __restrict__ cnt) {
    int t = blockIdx.x * blockDim.x + threadIdx.x;
    if (t >= 2 * NE) return;
    int col;
    if (t < NE) {
        int p = triples[3 * t + 1], o = triples[3 * t + 2];
        col = p * NN + o;
    } else {
        int i = t - NE;
        int s = triples[3 * i], p = triples[3 * i + 1];
        col = (p + NR) * NN + s;
    }
    atomicAdd(cnt + col, 1);
}

// ---------------- layer 1: h[dst] += val * w0[col,:]  (16 lanes/edge, f4) -----
__global__ __launch_bounds__(256) void layer1_kernel(const int* __restrict__ triples,
                                                     const float* __restrict__ w0,
                                                     const int* __restrict__ cnt,
                                                     float* __restrict__ h) {
    long long t = (long long)blockIdx.x * blockDim.x + threadIdx.x;
    int g = (int)(t >> 4), q = (int)(t & 15);
    if (g >= 2 * NE + NN) return;
    int dst, col; float val;
    if (g < NE) {
        int s = triples[3 * g], p = triples[3 * g + 1], o = triples[3 * g + 2];
        col = p * NN + o; dst = s; val = 1.0f / (float)cnt[col];
    } else if (g < 2 * NE) {
        int i = g - NE;
        int s = triples[3 * i], p = triples[3 * i + 1], o = triples[3 * i + 2];
        col = (p + NR) * NN + s; dst = o; val = 1.0f / (float)cnt[col];
    } else {
        int v = g - 2 * NE;
        col = 2 * NR * NN + v; dst = v; val = 1.0f;
    }
    const float4 wv = *(const float4*)(w0 + (size_t)col * HID + q * 4);
    float* hb = h + (size_t)dst * HID + q * 4;
    atomicAdd(hb + 0, val * wv.x);
    atomicAdd(hb + 1, val * wv.y);
    atomicAdd(hb + 2, val * wv.z);
    atomicAdd(hb + 3, val * wv.w);
}

// ---------------- h += b0 -----------------------------------------------------
__global__ void bias_kernel(float* __restrict__ h, const float* __restrict__ b0) {
    int t = blockIdx.x * blockDim.x + threadIdx.x;
    if (t < NN * HID) h[t] += b0[t & 63];
}

// ---------------- phase A: agg[ss][dst] += val * h[src]  (16 lanes/edge) ------
__global__ __launch_bounds__(256) void phaseA_kernel(const int* __restrict__ triples,
                                                     const float* __restrict__ h,
                                                     const int* __restrict__ cnt,
                                                     float* __restrict__ agg,
                                                     int c0, int c1) {
    long long t = (long long)blockIdx.x * blockDim.x + threadIdx.x;
    int g = (int)(t >> 4), q = (int)(t & 15);
    if (g >= 2 * NE) return;
    int src, dst, ss;
    if (g < NE) {
        int s = triples[3 * g], p = triples[3 * g + 1], o = triples[3 * g + 2];
        src = o; dst = s; ss = p;
    } else {
        int i = g - NE;
        int s = triples[3 * i], p = triples[3 * i + 1], o = triples[3 * i + 2];
        src = s; dst = o; ss = p + NR;
    }
    if (ss < c0 || ss >= c1) return;
    float val = 1.0f / (float)cnt[ss * NN + src];
    const float4 hv = *(const float4*)(h + (size_t)src * HID + q * 4);
    float* ab = agg + ((size_t)(ss - c0) * NN + dst) * HID + q * 4;
    atomicAdd(ab + 0, val * hv.x);
    atomicAdd(ab + 1, val * hv.y);
    atomicAdd(ab + 2, val * hv.z);
    atomicAdd(ab + 3, val * hv.w);
}

// ---------------- phase B: nodes += sum_r agg_r @ w1[r]  (+ self-loop last) ---
// 782 blocks x 256 thr; wave handles 16 rows, lane = output col.
__global__ __launch_bounds__(256) void phaseB_kernel(const float* __restrict__ agg,
                                                     const float* __restrict__ h,
                                                     const float* __restrict__ w1,
                                                     float* __restrict__ nodes,
                                                     int c0, int c1) {
    const int lane = threadIdx.x & 63;
    const int wid = __builtin_amdgcn_readfirstlane(threadIdx.x >> 6);
    const int base = blockIdx.x * 64 + wid * 16;

    float acc[16];
#pragma unroll
    for (int i = 0; i < 16; ++i) acc[i] = 0.f;

    const int nr = c1 - c0;
    for (int rl = 0; rl < nr; ++rl) {
        const float* wp = w1 + (size_t)(c0 + rl) * HID * HID;
        const float* ap = agg + (size_t)rl * NN * HID;
#pragma unroll
        for (int kc = 0; kc < 4; ++kc) {
            float wk[16];
#pragma unroll
            for (int k = 0; k < 16; ++k) wk[k] = wp[(kc * 16 + k) * HID + lane];
#pragma unroll 4
            for (int i = 0; i < 16; ++i) {
                int row = base + i;
                if (row < NN) {
                    const float* arow = ap + (size_t)row * HID + kc * 16;
                    float a = acc[i];
#pragma unroll
                    for (int k = 0; k < 16; ++k) a += arow[k] * wk[k];
                    acc[i] = a;
                }
            }
        }
    }

    if (c1 == 2 * NR) {   // final chunk: fold in self-loop  nodes += h @ w1[20]
        const float* wp = w1 + (size_t)(2 * NR) * HID * HID;
#pragma unroll
        for (int kc = 0; kc < 4; ++kc) {
            float wk[16];
#pragma unroll
            for (int k = 0; k < 16; ++k) wk[k] = wp[(kc * 16 + k) * HID + lane];
#pragma unroll 4
            for (int i = 0; i < 16; ++i) {
                int row = base + i;
                if (row < NN) {
                    const float* arow = h + (size_t)row * HID + kc * 16;
                    float a = acc[i];
#pragma unroll
                    for (int k = 0; k < 16; ++k) a += arow[k] * wk[k];
                    acc[i] = a;
                }
            }
        }
    }

#pragma unroll
    for (int i = 0; i < 16; ++i) {
        int row = base + i;
        if (row < NN) nodes[(size_t)row * HID + lane] += acc[i];
    }
}

// ---------------- scores: wave per batch item --------------------------------
__global__ __launch_bounds__(256) void score_kernel(const int* __restrict__ batch,
                                                    const float* __restrict__ nodes,
                                                    const float* __restrict__ b1,
                                                    const float* __restrict__ rel,
                                                    float* __restrict__ out) {
    int wave = (blockIdx.x * blockDim.x + threadIdx.x) >> 6;
    int lane = threadIdx.x & 63;
    if (wave >= NB) return;
    int si = batch[3 * wave], pi = batch[3 * wave + 1], oi = batch[3 * wave + 2];
    float a = nodes[si * HID + lane] + b1[lane];
    float b = nodes[oi * HID + lane] + b1[lane];
    float v = a * rel[pi * HID + lane] * b;
#pragma unroll
    for (int off = 32; off; off >>= 1) v += __shfl_down(v, off, 64);
    if (lane == 0) out[wave] = v;
}

extern "C" void kernel_launch(void* const* d_in, const int* in_sizes, int n_in,
                              void* d_out, int out_size, void* d_ws, size_t ws_size,
                              hipStream_t stream) {
    const int*   batch   = (const int*)d_in[0];
    const int*   triples = (const int*)d_in[1];
    const float* w0      = (const float*)d_in[2];
    const float* b0      = (const float*)d_in[3];
    const float* w1      = (const float*)d_in[4];
    const float* b1      = (const float*)d_in[5];
    const float* rel     = (const float*)d_in[6];
    float* out = (float*)d_out;

    const size_t slab = (size_t)NN * HID * 4;          // 12.8 MB
    char* ws = (char*)d_ws;
    int*   cnt   = (int*)ws;                           // 4.0 MB
    float* h     = (float*)(ws + (size_t)2 * NR * NN * 4);
    float* nodes = h + (size_t)NN * HID;
    float* agg   = nodes + (size_t)NN * HID;

    const size_t fixed = (size_t)2 * NR * NN * 4 + 2 * slab;
    long long avail = (long long)ws_size - (long long)fixed;
    int CH = (int)(avail / (long long)slab);
    if (CH > 2 * NR) CH = 2 * NR;
    if (CH < 1) CH = 1;

    // zero cnt + h + nodes (contiguous at start of ws)
    hipMemsetAsync(d_ws, 0, fixed, stream);

    count_kernel<<<(2 * NE + 255) / 256, 256, 0, stream>>>(triples, cnt);

    {
        long long tot = (long long)(2 * NE + NN) * 16;
        int blocks = (int)((tot + 255) / 256);
        layer1_kernel<<<blocks, 256, 0, stream>>>(triples, w0, cnt, h);
    }

    bias_kernel<<<(NN * HID + 255) / 256, 256, 0, stream>>>(h, b0);

    {
        long long tot = (long long)(2 * NE) * 16;
        int ablocks = (int)((tot + 255) / 256);
        int bblocks = (NN + 63) / 64;                  // 782
        for (int c0 = 0; c0 < 2 * NR; c0 += CH) {
            int c1 = c0 + CH; if (c1 > 2 * NR) c1 = 2 * NR;
            hipMemsetAsync(agg, 0, (size_t)(c1 - c0) * slab, stream);
            phaseA_kernel<<<ablocks, 256, 0, stream>>>(triples, h, cnt, agg, c0, c1);
            phaseB_kernel<<<bblocks, 256, 0, stream>>>(agg, h, w1, nodes, c0, c1);
        }
    }

    score_kernel<<<(NB * 64 + 255) / 256, 256, 0, stream>>>(batch, nodes, b1, rel, out);
}

// Round 3
// 1446.365 us; speedup vs baseline: 1.8826x; 1.8826x over previous
//
#include <hip/hip_runtime.h>

#define NN 50000      // nodes
#define NR 10         // relations (one direction)
#define R2 21         // 2*NR+1
#define NE 500000     // triples
#define NB 16384      // batch
#define HID 64
#define SCAN_B 1024

// ---- fused histogram: cnt[col], deg-by-dst (off1), deg-by-(rel,dst) (off2) ---
__global__ void hist_kernel(const int* __restrict__ triples, int* __restrict__ cnt,
                            int* __restrict__ off1, int* __restrict__ off2) {
    int t = blockIdx.x * blockDim.x + threadIdx.x;
    if (t >= 2 * NE + NN) return;
    if (t < 2 * NE) {
        int e = (t < NE) ? t : t - NE;
        int s = triples[3 * e], p = triples[3 * e + 1], o = triples[3 * e + 2];
        int ss, dst, src;
        if (t < NE) { ss = p;      dst = s; src = o; }
        else        { ss = p + NR; dst = o; src = s; }
        atomicAdd(cnt + ss * NN + src, 1);
        atomicAdd(off1 + dst, 1);
        atomicAdd(off2 + ss * NN + dst, 1);
    } else {
        int v = t - 2 * NE;
        cnt[2 * NR * NN + v] = 1;       // self-loop col count is always 1
        atomicAdd(off1 + v, 1);
    }
}

// ---- generic 2-level exclusive scan ------------------------------------------
__global__ void scan1_kernel(int* __restrict__ data, int* __restrict__ bsums, int M) {
    __shared__ int sm[SCAN_B];
    int i = blockIdx.x * SCAN_B + threadIdx.x;
    int x = (i < M) ? data[i] : 0;
    sm[threadIdx.x] = x; __syncthreads();
    for (int off = 1; off < SCAN_B; off <<= 1) {
        int v = (threadIdx.x >= off) ? sm[threadIdx.x - off] : 0;
        __syncthreads();
        sm[threadIdx.x] += v;
        __syncthreads();
    }
    if (i < M) data[i] = sm[threadIdx.x] - x;     // exclusive
    if (threadIdx.x == SCAN_B - 1) bsums[blockIdx.x] = sm[threadIdx.x];
}
__global__ void scan2_kernel(int* __restrict__ bsums, int nb, int* __restrict__ total_out) {
    __shared__ int sm[SCAN_B];
    int x = (threadIdx.x < nb) ? bsums[threadIdx.x] : 0;
    sm[threadIdx.x] = x; __syncthreads();
    for (int off = 1; off < SCAN_B; off <<= 1) {
        int v = (threadIdx.x >= off) ? sm[threadIdx.x - off] : 0;
        __syncthreads();
        sm[threadIdx.x] += v;
        __syncthreads();
    }
    if (threadIdx.x < nb) bsums[threadIdx.x] = sm[threadIdx.x] - x;
    if (threadIdx.x == SCAN_B - 1) *total_out = sm[SCAN_B - 1];
}
__global__ void scan3_kernel(int* __restrict__ data, const int* __restrict__ bsums, int M) {
    int i = blockIdx.x * SCAN_B + threadIdx.x;
    if (i < M) data[i] += bsums[blockIdx.x];
}

// ---- fused scatter into both sorted orders -----------------------------------
__global__ void scatter_kernel(const int* __restrict__ triples,
                               int* __restrict__ cur1, int* __restrict__ cur2,
                               int* __restrict__ pay1, int* __restrict__ pay2) {
    int t = blockIdx.x * blockDim.x + threadIdx.x;
    if (t >= 2 * NE + NN) return;
    if (t < 2 * NE) {
        int e = (t < NE) ? t : t - NE;
        int s = triples[3 * e], p = triples[3 * e + 1], o = triples[3 * e + 2];
        int ss, dst, src;
        if (t < NE) { ss = p;      dst = s; src = o; }
        else        { ss = p + NR; dst = o; src = s; }
        int p1 = atomicAdd(cur1 + dst, 1);
        pay1[p1] = ss * NN + src;                 // col
        int p2 = atomicAdd(cur2 + ss * NN + dst, 1);
        pay2[p2] = src;
    } else {
        int v = t - 2 * NE;
        int p1 = atomicAdd(cur1 + v, 1);
        pay1[p1] = 2 * NR * NN + v;               // self-loop col
    }
}

// ---- layer 1: wave per dst, register accumulate, single store ----------------
__global__ __launch_bounds__(256) void layer1_kernel(const int* __restrict__ off1,
                                                     const int* __restrict__ pay1,
                                                     const int* __restrict__ cnt,
                                                     const float* __restrict__ w0,
                                                     const float* __restrict__ b0,
                                                     float* __restrict__ h) {
    int wv = (blockIdx.x * blockDim.x + threadIdx.x) >> 6;
    int lane = threadIdx.x & 63;
    if (wv >= NN) return;
    int dst = __builtin_amdgcn_readfirstlane(wv);
    int beg = off1[dst], end = off1[dst + 1];
    float acc = b0[lane];
    for (int e = beg; e < end; ++e) {
        int col = __builtin_amdgcn_readfirstlane(pay1[e]);
        float val = 1.0f / (float)cnt[col];
        acc += val * w0[(size_t)col * HID + lane];
    }
    h[(size_t)dst * HID + lane] = acc;
}

// ---- phase A: wave per (rel,dst) cell; plain store (zeros for empty cells) ---
__global__ __launch_bounds__(256) void phaseA_kernel(const int* __restrict__ off2,
                                                     const int* __restrict__ pay2,
                                                     const int* __restrict__ cnt,
                                                     const float* __restrict__ h,
                                                     float* __restrict__ agg,
                                                     int c0, int ncells) {
    int wv = (blockIdx.x * blockDim.x + threadIdx.x) >> 6;
    int lane = threadIdx.x & 63;
    if (wv >= ncells) return;
    int c = __builtin_amdgcn_readfirstlane(wv);
    int cell = c0 * NN + c;
    int ss = cell / NN;
    int beg = off2[cell], end = off2[cell + 1];
    float acc = 0.f;
    for (int e = beg; e < end; ++e) {
        int src = __builtin_amdgcn_readfirstlane(pay2[e]);
        float val = 1.0f / (float)cnt[ss * NN + src];
        acc += val * h[(size_t)src * HID + lane];
    }
    agg[(size_t)c * HID + lane] = acc;
}

// ---- phase B: nodes (=|+=) sum_r agg_r @ w1[r]  (+ self-loop on last chunk) --
__global__ __launch_bounds__(256) void phaseB_kernel(const float* __restrict__ agg,
                                                     const float* __restrict__ h,
                                                     const float* __restrict__ w1,
                                                     float* __restrict__ nodes,
                                                     int c0, int c1) {
    const int lane = threadIdx.x & 63;
    const int wid = __builtin_amdgcn_readfirstlane(threadIdx.x >> 6);
    const int base = blockIdx.x * 64 + wid * 16;

    float acc[16];
#pragma unroll
    for (int i = 0; i < 16; ++i) acc[i] = 0.f;

    const int nr = c1 - c0;
    for (int rl = 0; rl < nr; ++rl) {
        const float* wp = w1 + (size_t)(c0 + rl) * HID * HID;
        const float* ap = agg + (size_t)rl * NN * HID;
#pragma unroll
        for (int kc = 0; kc < 4; ++kc) {
            float wk[16];
#pragma unroll
            for (int k = 0; k < 16; ++k) wk[k] = wp[(kc * 16 + k) * HID + lane];
#pragma unroll 4
            for (int i = 0; i < 16; ++i) {
                int row = base + i;
                if (row < NN) {
                    const float* arow = ap + (size_t)row * HID + kc * 16;
                    float a = acc[i];
#pragma unroll
                    for (int k = 0; k < 16; ++k) a += arow[k] * wk[k];
                    acc[i] = a;
                }
            }
        }
    }

    if (c1 == 2 * NR) {   // last chunk: fold in self-loop  nodes += h @ w1[20]
        const float* wp = w1 + (size_t)(2 * NR) * HID * HID;
#pragma unroll
        for (int kc = 0; kc < 4; ++kc) {
            float wk[16];
#pragma unroll
            for (int k = 0; k < 16; ++k) wk[k] = wp[(kc * 16 + k) * HID + lane];
#pragma unroll 4
            for (int i = 0; i < 16; ++i) {
                int row = base + i;
                if (row < NN) {
                    const float* arow = h + (size_t)row * HID + kc * 16;
                    float a = acc[i];
#pragma unroll
                    for (int k = 0; k < 16; ++k) a += arow[k] * wk[k];
                    acc[i] = a;
                }
            }
        }
    }

#pragma unroll
    for (int i = 0; i < 16; ++i) {
        int row = base + i;
        if (row < NN) {
            if (c0 == 0) nodes[(size_t)row * HID + lane] = acc[i];
            else         nodes[(size_t)row * HID + lane] += acc[i];
        }
    }
}

// ---- scores: wave per batch item ---------------------------------------------
__global__ __launch_bounds__(256) void score_kernel(const int* __restrict__ batch,
                                                    const float* __restrict__ nodes,
                                                    const float* __restrict__ b1,
                                                    const float* __restrict__ rel,
                                                    float* __restrict__ out) {
    int wave = (blockIdx.x * blockDim.x + threadIdx.x) >> 6;
    int lane = threadIdx.x & 63;
    if (wave >= NB) return;
    int si = batch[3 * wave], pi = batch[3 * wave + 1], oi = batch[3 * wave + 2];
    float a = nodes[si * HID + lane] + b1[lane];
    float b = nodes[oi * HID + lane] + b1[lane];
    float v = a * rel[pi * HID + lane] * b;
#pragma unroll
    for (int off = 32; off; off >>= 1) v += __shfl_down(v, off, 64);
    if (lane == 0) out[wave] = v;
}

extern "C" void kernel_launch(void* const* d_in, const int* in_sizes, int n_in,
                              void* d_out, int out_size, void* d_ws, size_t ws_size,
                              hipStream_t stream) {
    const int*   batch   = (const int*)d_in[0];
    const int*   triples = (const int*)d_in[1];
    const float* w0      = (const float*)d_in[2];
    const float* b0      = (const float*)d_in[3];
    const float* w1      = (const float*)d_in[4];
    const float* b1      = (const float*)d_in[5];
    const float* rel     = (const float*)d_in[6];
    float* out = (float*)d_out;

    // ---- workspace layout (zero region first: cnt|off1|off2 contiguous) ----
    int* cnt  = (int*)d_ws;                    // R2*NN        = 1,050,000
    int* off1 = cnt + (size_t)R2 * NN;         // NN+1         = 50,001
    int* off2 = off1 + (NN + 1);               // 20*NN+1      = 1,000,001
    int* cur1 = off2 + (20 * NN + 1);          // NN
    int* cur2 = cur1 + NN;                     // 20*NN
    int* pay1 = cur2 + 20 * NN;                // 2NE+NN       = 1,050,000
    int* pay2 = pay1 + (2 * NE + NN);          // 2NE          = 1,000,000
    int* sums = pay2 + 2 * NE;                 // 1024
    float* h     = (float*)(sums + 1024);      // NN*HID
    float* nodes = h + (size_t)NN * HID;       // NN*HID
    float* agg   = nodes + (size_t)NN * HID;   // CH*NN*HID

    const size_t slab = (size_t)NN * HID * 4;  // 12.8 MB
    size_t fixed_bytes = (size_t)((char*)agg - (char*)d_ws);
    long long avail = (long long)ws_size - (long long)fixed_bytes;
    int CH = (int)(avail / (long long)slab);
    if (CH > 4) CH = 4;
    if (CH < 1) CH = 1;

    size_t zero_bytes = (size_t)(R2 * NN + (NN + 1) + (20 * NN + 1)) * 4;  // 8.4 MB
    hipMemsetAsync(d_ws, 0, zero_bytes, stream);

    int tot = 2 * NE + NN;
    hist_kernel<<<(tot + 255) / 256, 256, 0, stream>>>(triples, cnt, off1, off2);

    {   // scan off1 (M = NN), total -> off1[NN]
        int M = NN, nb = (M + SCAN_B - 1) / SCAN_B;   // 49
        scan1_kernel<<<nb, SCAN_B, 0, stream>>>(off1, sums, M);
        scan2_kernel<<<1, SCAN_B, 0, stream>>>(sums, nb, off1 + M);
        scan3_kernel<<<nb, SCAN_B, 0, stream>>>(off1, sums, M);
    }
    {   // scan off2 (M = 20*NN), total -> off2[20*NN]
        int M = 20 * NN, nb = (M + SCAN_B - 1) / SCAN_B;  // 977
        scan1_kernel<<<nb, SCAN_B, 0, stream>>>(off2, sums, M);
        scan2_kernel<<<1, SCAN_B, 0, stream>>>(sums, nb, off2 + M);
        scan3_kernel<<<nb, SCAN_B, 0, stream>>>(off2, sums, M);
    }

    hipMemcpyAsync(cur1, off1, (size_t)NN * 4, hipMemcpyDeviceToDevice, stream);
    hipMemcpyAsync(cur2, off2, (size_t)20 * NN * 4, hipMemcpyDeviceToDevice, stream);

    scatter_kernel<<<(tot + 255) / 256, 256, 0, stream>>>(triples, cur1, cur2, pay1, pay2);

    layer1_kernel<<<(NN * 64 + 255) / 256, 256, 0, stream>>>(off1, pay1, cnt, w0, b0, h);

    {
        int bblocks = (NN + 63) / 64;                  // 782
        for (int c0 = 0; c0 < 2 * NR; c0 += CH) {
            int c1 = c0 + CH; if (c1 > 2 * NR) c1 = 2 * NR;
            int ncells = (c1 - c0) * NN;
            int ablocks = (ncells * 64 + 255) / 256;
            phaseA_kernel<<<ablocks, 256, 0, stream>>>(off2, pay2, cnt, h, agg, c0, ncells);
            phaseB_kernel<<<bblocks, 256, 0, stream>>>(agg, h, w1, nodes, c0, c1);
        }
    }

    score_kernel<<<(NB * 64 + 255) / 256, 256, 0, stream>>>(batch, nodes, b1, rel, out);
}

// Round 4
// 1162.733 us; speedup vs baseline: 2.3418x; 1.2439x over previous
//
#include <hip/hip_runtime.h>

#define NN 50000      // nodes
#define NR 10         // relations (one direction)
#define R2 21         // 2*NR+1
#define NE 500000     // triples
#define NB 16384      // batch
#define HID 64
#define SCAN_B 1024   // threads per scan block; 2 items/thread -> 2048 elems/block

// ---- hist: cnt[ss*NN+src] ++, cell count (dst*21+ss) ++ with rank capture ----
__global__ void hist_kernel(const int* __restrict__ triples, int* __restrict__ cnt,
                            int* __restrict__ celloff, int* __restrict__ rank) {
    int t = blockIdx.x * blockDim.x + threadIdx.x;
    if (t >= 2 * NE + NN) return;
    if (t < 2 * NE) {
        int e = (t < NE) ? t : t - NE;
        int s = triples[3 * e], p = triples[3 * e + 1], o = triples[3 * e + 2];
        int ss, dst, src;
        if (t < NE) { ss = p;      dst = s; src = o; }
        else        { ss = p + NR; dst = o; src = s; }
        rank[t] = atomicAdd(celloff + dst * R2 + ss, 1);
        atomicAdd(cnt + ss * NN + src, 1);
    } else {
        int v = t - 2 * NE;
        celloff[v * R2 + 2 * NR] = 1;   // self-loop cell: always exactly 1
        cnt[2 * NR * NN + v] = 1;       // self-loop col count: always 1
    }
}

// ---- cnt -> 1/cnt (float, in place) ------------------------------------------
__global__ void recip_kernel(int* __restrict__ cnt) {
    int i = blockIdx.x * blockDim.x + threadIdx.x;
    if (i < R2 * NN) {
        int c = cnt[i];
        ((float*)cnt)[i] = 1.0f / (float)c;
    }
}

// ---- 2-level exclusive scan, 2 items per thread ------------------------------
__global__ void scan1_kernel(int* __restrict__ data, int* __restrict__ bsums, int M) {
    __shared__ int sm[SCAN_B];
    int i0 = (blockIdx.x * SCAN_B + threadIdx.x) * 2;
    int x0 = (i0     < M) ? data[i0]     : 0;
    int x1 = (i0 + 1 < M) ? data[i0 + 1] : 0;
    int s = x0 + x1;
    sm[threadIdx.x] = s; __syncthreads();
    for (int off = 1; off < SCAN_B; off <<= 1) {
        int v = (threadIdx.x >= off) ? sm[threadIdx.x - off] : 0;
        __syncthreads();
        sm[threadIdx.x] += v;
        __syncthreads();
    }
    int excl = sm[threadIdx.x] - s;
    if (i0     < M) data[i0]     = excl;
    if (i0 + 1 < M) data[i0 + 1] = excl + x0;
    if (threadIdx.x == SCAN_B - 1) bsums[blockIdx.x] = sm[SCAN_B - 1];
}
__global__ void scan2_kernel(int* __restrict__ bsums, int nb, int* __restrict__ total_out) {
    __shared__ int sm[SCAN_B];
    int x = (threadIdx.x < nb) ? bsums[threadIdx.x] : 0;
    sm[threadIdx.x] = x; __syncthreads();
    for (int off = 1; off < SCAN_B; off <<= 1) {
        int v = (threadIdx.x >= off) ? sm[threadIdx.x - off] : 0;
        __syncthreads();
        sm[threadIdx.x] += v;
        __syncthreads();
    }
    if (threadIdx.x < nb) bsums[threadIdx.x] = sm[threadIdx.x] - x;
    if (threadIdx.x == SCAN_B - 1) *total_out = sm[SCAN_B - 1];
}
__global__ void scan3_kernel(int* __restrict__ data, const int* __restrict__ bsums, int M) {
    int i0 = (blockIdx.x * SCAN_B + threadIdx.x) * 2;
    int b = bsums[blockIdx.x];
    if (i0     < M) data[i0]     += b;
    if (i0 + 1 < M) data[i0 + 1] += b;
}

// ---- scatter (atomic-free via rank): pay[off[key]+rank] = ss*NN+src ----------
__global__ void scatter_kernel(const int* __restrict__ triples,
                               const int* __restrict__ celloff,
                               const int* __restrict__ rank,
                               int* __restrict__ pay) {
    int t = blockIdx.x * blockDim.x + threadIdx.x;
    if (t >= 2 * NE + NN) return;
    if (t < 2 * NE) {
        int e = (t < NE) ? t : t - NE;
        int s = triples[3 * e], p = triples[3 * e + 1], o = triples[3 * e + 2];
        int ss, dst, src;
        if (t < NE) { ss = p;      dst = s; src = o; }
        else        { ss = p + NR; dst = o; src = s; }
        int pos = celloff[dst * R2 + ss] + rank[t];
        pay[pos] = ss * NN + src;
    } else {
        int v = t - 2 * NE;
        int pos = celloff[v * R2 + 2 * NR];
        pay[pos] = 2 * NR * NN + v;
    }
}

// ---- layer 1: wave per dst; lane-parallel edge fetch; ILP-4 w0 row loads -----
__global__ __launch_bounds__(256) void layer1_kernel(const int* __restrict__ celloff,
                                                     const int* __restrict__ pay,
                                                     const float* __restrict__ vals,
                                                     const float* __restrict__ w0,
                                                     const float* __restrict__ b0,
                                                     float* __restrict__ h) {
    int wv = (blockIdx.x * blockDim.x + threadIdx.x) >> 6;
    int lane = threadIdx.x & 63;
    if (wv >= NN) return;
    int dst = __builtin_amdgcn_readfirstlane(wv);
    int beg = celloff[dst * R2];
    int end = celloff[(dst + 1) * R2];
    float acc = b0[lane];
    for (int base = beg; base < end; base += 64) {
        int idx = base + lane;
        int colv = (idx < end) ? pay[idx] : 2 * NR * NN;  // dummy valid col
        float vv = (idx < end) ? vals[colv] : 0.f;
        int m = __builtin_amdgcn_readfirstlane(min(64, end - base));
        int e = 0;
        for (; e + 4 <= m; e += 4) {
            int   c0_ = __shfl(colv, e,     64); float v0 = __shfl(vv, e,     64);
            int   c1_ = __shfl(colv, e + 1, 64); float v1 = __shfl(vv, e + 1, 64);
            int   c2_ = __shfl(colv, e + 2, 64); float v2 = __shfl(vv, e + 2, 64);
            int   c3_ = __shfl(colv, e + 3, 64); float v3 = __shfl(vv, e + 3, 64);
            float f0 = w0[(size_t)c0_ * HID + lane];
            float f1 = w0[(size_t)c1_ * HID + lane];
            float f2 = w0[(size_t)c2_ * HID + lane];
            float f3 = w0[(size_t)c3_ * HID + lane];
            acc += v0 * f0; acc += v1 * f1; acc += v2 * f2; acc += v3 * f3;
        }
        for (; e < m; ++e) {
            int   c = __shfl(colv, e, 64);
            float v = __shfl(vv, e, 64);
            acc += v * w0[(size_t)c * HID + lane];
        }
    }
    h[(size_t)dst * HID + lane] = acc;
}

// ---- phase A: wave per dst, 4 relation-accumulators in regs, plain stores ----
__global__ __launch_bounds__(256) void phaseA_kernel(const int* __restrict__ celloff,
                                                     const int* __restrict__ pay,
                                                     const float* __restrict__ vals,
                                                     const float* __restrict__ h,
                                                     float* __restrict__ agg,
                                                     int c0, int c1) {
    int wv = (blockIdx.x * blockDim.x + threadIdx.x) >> 6;
    int lane = threadIdx.x & 63;
    if (wv >= NN) return;
    int dst = __builtin_amdgcn_readfirstlane(wv);
    int beg = celloff[dst * R2 + c0];
    int end = celloff[dst * R2 + c1];
    float a0 = 0.f, a1 = 0.f, a2 = 0.f, a3 = 0.f;
    for (int e = beg; e < end; ++e) {
        int col = __builtin_amdgcn_readfirstlane(pay[e]);
        int ss = col / NN;
        int src = col - ss * NN;
        float val = vals[col];
        float m = val * h[(size_t)src * HID + lane];
        int j = ss - c0;
        if (j == 0) a0 += m; else if (j == 1) a1 += m;
        else if (j == 2) a2 += m; else a3 += m;
    }
    int nr = c1 - c0;
    float* ab = agg + (size_t)dst * HID + lane;
    if (nr > 0) ab[0 * (size_t)NN * HID] = a0;
    if (nr > 1) ab[1 * (size_t)NN * HID] = a1;
    if (nr > 2) ab[2 * (size_t)NN * HID] = a2;
    if (nr > 3) ab[3 * (size_t)NN * HID] = a3;
}

// ---- phase B: nodes (=|+=) sum_r agg_r @ w1[r]  (+ self-loop on last chunk) --
__global__ __launch_bounds__(256) void phaseB_kernel(const float* __restrict__ agg,
                                                     const float* __restrict__ h,
                                                     const float* __restrict__ w1,
                                                     float* __restrict__ nodes,
                                                     int c0, int c1) {
    const int lane = threadIdx.x & 63;
    const int wid = __builtin_amdgcn_readfirstlane(threadIdx.x >> 6);
    const int base = blockIdx.x * 64 + wid * 16;

    float acc[16];
#pragma unroll
    for (int i = 0; i < 16; ++i) acc[i] = 0.f;

    const int nr = c1 - c0;
    for (int rl = 0; rl < nr; ++rl) {
        const float* wp = w1 + (size_t)(c0 + rl) * HID * HID;
        const float* ap = agg + (size_t)rl * NN * HID;
#pragma unroll
        for (int kc = 0; kc < 4; ++kc) {
            float wk[16];
#pragma unroll
            for (int k = 0; k < 16; ++k) wk[k] = wp[(kc * 16 + k) * HID + lane];
#pragma unroll 4
            for (int i = 0; i < 16; ++i) {
                int row = base + i;
                if (row < NN) {
                    const float* arow = ap + (size_t)row * HID + kc * 16;
                    float a = acc[i];
#pragma unroll
                    for (int k = 0; k < 16; ++k) a += arow[k] * wk[k];
                    acc[i] = a;
                }
            }
        }
    }

    if (c1 == 2 * NR) {   // last chunk: fold in self-loop  nodes += h @ w1[20]
        const float* wp = w1 + (size_t)(2 * NR) * HID * HID;
#pragma unroll
        for (int kc = 0; kc < 4; ++kc) {
            float wk[16];
#pragma unroll
            for (int k = 0; k < 16; ++k) wk[k] = wp[(kc * 16 + k) * HID + lane];
#pragma unroll 4
            for (int i = 0; i < 16; ++i) {
                int row = base + i;
                if (row < NN) {
                    const float* arow = h + (size_t)row * HID + kc * 16;
                    float a = acc[i];
#pragma unroll
                    for (int k = 0; k < 16; ++k) a += arow[k] * wk[k];
                    acc[i] = a;
                }
            }
        }
    }

#pragma unroll
    for (int i = 0; i < 16; ++i) {
        int row = base + i;
        if (row < NN) {
            if (c0 == 0) nodes[(size_t)row * HID + lane] = acc[i];
            else         nodes[(size_t)row * HID + lane] += acc[i];
        }
    }
}

// ---- scores: wave per batch item ---------------------------------------------
__global__ __launch_bounds__(256) void score_kernel(const int* __restrict__ batch,
                                                    const float* __restrict__ nodes,
                                                    const float* __restrict__ b1,
                                                    const float* __restrict__ rel,
                                                    float* __restrict__ out) {
    int wave = (blockIdx.x * blockDim.x + threadIdx.x) >> 6;
    int lane = threadIdx.x & 63;
    if (wave >= NB) return;
    int si = batch[3 * wave], pi = batch[3 * wave + 1], oi = batch[3 * wave + 2];
    float a = nodes[si * HID + lane] + b1[lane];
    float b = nodes[oi * HID + lane] + b1[lane];
    float v = a * rel[pi * HID + lane] * b;
#pragma unroll
    for (int off = 32; off; off >>= 1) v += __shfl_down(v, off, 64);
    if (lane == 0) out[wave] = v;
}

extern "C" void kernel_launch(void* const* d_in, const int* in_sizes, int n_in,
                              void* d_out, int out_size, void* d_ws, size_t ws_size,
                              hipStream_t stream) {
    const int*   batch   = (const int*)d_in[0];
    const int*   triples = (const int*)d_in[1];
    const float* w0      = (const float*)d_in[2];
    const float* b0      = (const float*)d_in[3];
    const float* w1      = (const float*)d_in[4];
    const float* b1      = (const float*)d_in[5];
    const float* rel     = (const float*)d_in[6];
    float* out = (float*)d_out;

    // ---- workspace layout (zero region first: cnt | celloff contiguous) ----
    int* cnt     = (int*)d_ws;                    // R2*NN   = 1,050,000 (-> vals)
    int* celloff = cnt + (size_t)R2 * NN;         // R2*NN+1 = 1,050,001
    int* rank    = celloff + ((size_t)R2 * NN + 1); // 2NE   = 1,000,000
    int* pay     = rank + 2 * NE;                 // 2NE+NN  = 1,050,000
    int* sums    = pay + (2 * NE + NN);           // 1024
    float* h     = (float*)(sums + SCAN_B);       // NN*HID
    float* nodes = h + (size_t)NN * HID;          // NN*HID
    float* agg   = nodes + (size_t)NN * HID;      // CH*NN*HID
    const float* vals = (const float*)cnt;

    const size_t slab = (size_t)NN * HID * 4;     // 12.8 MB
    size_t fixed_bytes = (size_t)((char*)agg - (char*)d_ws);
    long long avail = (long long)ws_size - (long long)fixed_bytes;
    int CH = (int)(avail / (long long)slab);
    if (CH > 4) CH = 4;
    if (CH < 1) CH = 1;

    size_t zero_bytes = (size_t)(2 * R2 * NN + 1) * 4;   // cnt + celloff, 8.4 MB
    hipMemsetAsync(d_ws, 0, zero_bytes, stream);

    const int tot = 2 * NE + NN;
    hist_kernel<<<(tot + 255) / 256, 256, 0, stream>>>(triples, cnt, celloff, rank);
    recip_kernel<<<(R2 * NN + 255) / 256, 256, 0, stream>>>(cnt);

    {   // exclusive scan of celloff (M = R2*NN), total -> celloff[M]
        int M = R2 * NN;
        int nb = (M + 2 * SCAN_B - 1) / (2 * SCAN_B);    // 513
        scan1_kernel<<<nb, SCAN_B, 0, stream>>>(celloff, sums, M);
        scan2_kernel<<<1, SCAN_B, 0, stream>>>(sums, nb, celloff + M);
        scan3_kernel<<<nb, SCAN_B, 0, stream>>>(celloff, sums, M);
    }

    scatter_kernel<<<(tot + 255) / 256, 256, 0, stream>>>(triples, celloff, rank, pay);

    layer1_kernel<<<(NN * 64 + 255) / 256, 256, 0, stream>>>(celloff, pay, vals, w0, b0, h);

    {
        int ablocks = (NN * 64 + 255) / 256;             // 12500
        int bblocks = (NN + 63) / 64;                    // 782
        for (int c0 = 0; c0 < 2 * NR; c0 += CH) {
            int c1 = c0 + CH; if (c1 > 2 * NR) c1 = 2 * NR;
            phaseA_kernel<<<ablocks, 256, 0, stream>>>(celloff, pay, vals, h, agg, c0, c1);
            phaseB_kernel<<<bblocks, 256, 0, stream>>>(agg, h, w1, nodes, c0, c1);
        }
    }

    score_kernel<<<(NB * 64 + 255) / 256, 256, 0, stream>>>(batch, nodes, b1, rel, out);
}